// Round 13
// baseline (146.181 us; speedup 1.0000x reference)
//
#include <hip/hip_runtime.h>

// B=4, H=W=64, D=256, N=8, K=V=32, H2=W2=32, HW=4096, M=1024 pooled/batch.

typedef _Float16 f16x8 __attribute__((ext_vector_type(8)));
typedef _Float16 f16x4 __attribute__((ext_vector_type(4)));
typedef float    f32x4 __attribute__((ext_vector_type(4)));

#define F16(x) static_cast<_Float16>(x)

#if __has_builtin(__builtin_amdgcn_exp2f)
#define EXP2(x) __builtin_amdgcn_exp2f(x)
#else
#define EXP2(x) exp2f(x)
#endif

// async global->LDS DMA, 16 B per lane; lane i lands at (uniform base) + i*16
__device__ __forceinline__ void gl_lds16(const void* g, void* l) {
    __builtin_amdgcn_global_load_lds(
        (const __attribute__((address_space(1))) unsigned int*)g,
        (__attribute__((address_space(3))) unsigned int*)l, 16, 0, 0);
}

// ---------------- prep: weights -> f16 transposed Wt[mat][o][d] -------------
// LDS 32x33 tile transpose: coalesced f32 reads along o, contiguous f16
// writes along d.
__global__ __launch_bounds__(256) void prep_kernel(
    const float* __restrict__ wq, const float* __restrict__ wk,
    const float* __restrict__ wv, _Float16* __restrict__ wt) {
    __shared__ float t[32][33];
    const int blk = blockIdx.x;              // 192 = 3 mats x 64 tiles
    const int mat = blk >> 6;
    const int tile = blk & 63;
    const int d0 = (tile >> 3) * 32, o0 = (tile & 7) * 32;
    const float* w = (mat == 0) ? wq : (mat == 1 ? wk : wv);
    const int tx = threadIdx.x & 31, ty = threadIdx.x >> 5;   // ty 0..7
#pragma unroll
    for (int i = 0; i < 4; ++i)
        t[ty + i * 8][tx] = w[(d0 + ty + i * 8) * 256 + o0 + tx];
    __syncthreads();
#pragma unroll
    for (int i = 0; i < 4; ++i)
        wt[(mat << 16) + (o0 + ty + i * 8) * 256 + d0 + tx] = (_Float16)t[tx][ty + i * 8];
}

// ---------------- proj: all three 1x1-conv GEMMs in one launch --------------
// R9-verified: 64-row blocks, A LDS depth-2 pipeline, W register TRIPLE
// buffer (2-step prefetch distance -- covered the W L2 latency, -8 us).
// V output written FRAGMENT-ORDERED for attn (vf layout, validated round 4):
//   vf[bn][key>>4][lam*8 + (v>>4)*4 + (key&3)], lam = (v&15) + ((key>>2)&3)*16.
__global__ __launch_bounds__(256) void proj_kernel(
    const float* __restrict__ blob, const _Float16* __restrict__ wt,
    const float* __restrict__ bq, const float* __restrict__ bk, const float* __restrict__ bv,
    _Float16* __restrict__ qo, _Float16* __restrict__ ko, _Float16* __restrict__ vo) {
    __shared__ __align__(16) char atile[2][4096];   // [buf][64 rows x 32 k f16]

    const int tid = threadIdx.x;
    const int lane = tid & 63, wid = tid >> 6;
    const int quad = lane >> 4, l16 = lane & 15;
    int jb = blockIdx.x;                     // 576 = 64 q + 256 k + 256 v
    int job, rowblk;
    if (jb < 64)       { job = 0; rowblk = jb; }
    else if (jb < 320) { job = 1; rowblk = jb - 64; }
    else               { job = 2; rowblk = jb - 320; }
    const int rowbase = rowblk * 64;
    const int colbase = wid * 64;
    const _Float16* wmat = wt + ((size_t)job << 16);
    const float* bias = (job == 0) ? bq : (job == 1 ? bk : bv);

    // ---- staging assignment: 256 threads x 16 B granule of the A tile ----
    const int srow = tid >> 2, sc8 = tid & 3;            // row 0..63, 8-elem col
    const int sslot = srow * 4 + ((sc8 + (srow >> 2)) & 3);
    const float* aptr;                                    // global src base
    if (job == 0) {
        const int grow = rowbase + srow;
        const int bb = grow >> 10, y = (grow >> 5) & 31, x = grow & 31;
        aptr = blob + (((bb * 64 + 2 * y) * 64) + 2 * x) * 256 + sc8 * 8;
    } else {
        aptr = blob + (size_t)(rowbase + srow) * 256 + sc8 * 8;
    }

    // per-wave weight pointers
    const _Float16* wptr[4];
#pragma unroll
    for (int nt = 0; nt < 4; ++nt)
        wptr[nt] = wmat + (size_t)(colbase + nt * 16 + l16) * 256 + quad * 8;

    // af read base (per-lane, swizzled; mc adds 1024 B)
    const int aread = l16 * 64 + ((quad + (l16 >> 2)) & 3) * 16;

    f32x4 acc[4][4];
#pragma unroll
    for (int mc = 0; mc < 4; ++mc)
#pragma unroll
        for (int nt = 0; nt < 4; ++nt) acc[mc][nt] = (f32x4){0.f, 0.f, 0.f, 0.f};

    f16x8 wf[3][4];      // weight TRIPLE buffer (2-step prefetch distance)
    float4 ar[2][2];     // A-load double-buffer (8 f32 = one 16 B granule)

    auto A_LOAD = [&](int t, float4* dst) {
        const float* p = aptr + t * 32;
        if (job == 0) {
            float4 a0 = *(const float4*)(p);
            float4 a1 = *(const float4*)(p + 4);
            float4 b0 = *(const float4*)(p + 256);
            float4 b1 = *(const float4*)(p + 260);
            float4 c0 = *(const float4*)(p + 16384);
            float4 c1 = *(const float4*)(p + 16388);
            float4 d0 = *(const float4*)(p + 16640);
            float4 d1 = *(const float4*)(p + 16644);
            dst[0].x = fmaxf(fmaxf(a0.x, b0.x), fmaxf(c0.x, d0.x));
            dst[0].y = fmaxf(fmaxf(a0.y, b0.y), fmaxf(c0.y, d0.y));
            dst[0].z = fmaxf(fmaxf(a0.z, b0.z), fmaxf(c0.z, d0.z));
            dst[0].w = fmaxf(fmaxf(a0.w, b0.w), fmaxf(c0.w, d0.w));
            dst[1].x = fmaxf(fmaxf(a1.x, b1.x), fmaxf(c1.x, d1.x));
            dst[1].y = fmaxf(fmaxf(a1.y, b1.y), fmaxf(c1.y, d1.y));
            dst[1].z = fmaxf(fmaxf(a1.z, b1.z), fmaxf(c1.z, d1.z));
            dst[1].w = fmaxf(fmaxf(a1.w, b1.w), fmaxf(c1.w, d1.w));
        } else {
            dst[0] = *(const float4*)(p);
            dst[1] = *(const float4*)(p + 4);
        }
    };
    auto A_WRITE = [&](int buf, const float4* src) {
        auto c0 = __builtin_amdgcn_cvt_pkrtz(src[0].x, src[0].y);
        auto c1 = __builtin_amdgcn_cvt_pkrtz(src[0].z, src[0].w);
        auto c2 = __builtin_amdgcn_cvt_pkrtz(src[1].x, src[1].y);
        auto c3 = __builtin_amdgcn_cvt_pkrtz(src[1].z, src[1].w);
        f16x8 v = {F16(c0[0]), F16(c0[1]), F16(c1[0]), F16(c1[1]),
                   F16(c2[0]), F16(c2[1]), F16(c3[0]), F16(c3[1])};
        *(f16x8*)(atile[buf] + sslot * 16) = v;
    };
    auto W_LOAD = [&](int t, f16x8* dst) {
#pragma unroll
        for (int nt = 0; nt < 4; ++nt) dst[nt] = *(const f16x8*)(wptr[nt] + t * 32);
    };

    // ---- prologue: W 2 steps deep, A depth-2 ----
    W_LOAD(0, wf[0]);
    W_LOAD(1, wf[1]);
    A_LOAD(0, ar[0]);
    A_WRITE(0, ar[0]);
    A_LOAD(1, ar[1]);
    asm volatile("s_waitcnt lgkmcnt(0)\n\ts_barrier" ::: "memory");

#pragma unroll
    for (int s = 0; s < 8; ++s) {
        if (s < 6) W_LOAD(s + 2, wf[(s + 2) % 3]);   // 2-step W lookahead
        f16x8 af[4];
#pragma unroll
        for (int mc = 0; mc < 4; ++mc)
            af[mc] = *(const f16x8*)(atile[s & 1] + mc * 1024 + aread);
#pragma unroll
        for (int mc = 0; mc < 4; ++mc)
#pragma unroll
            for (int nt = 0; nt < 4; ++nt)
                acc[mc][nt] = __builtin_amdgcn_mfma_f32_16x16x32_f16(
                    af[mc], wf[s % 3][nt], acc[mc][nt], 0, 0, 0);
        if (s < 7) A_WRITE((s + 1) & 1, ar[(s + 1) & 1]);
        if (s < 6) A_LOAD(s + 2, ar[s & 1]);
        if (s < 7) asm volatile("s_waitcnt lgkmcnt(0)\n\ts_barrier" ::: "memory");
    }

    // ---- epilogue: bias / scale / swish + stores ----
#pragma unroll
    for (int nt = 0; nt < 4; ++nt) {
        const int o = colbase + nt * 16 + l16;
        const float bs = bias[o];
        const int nh = o >> 5, kk = o & 31;
#pragma unroll
        for (int mc = 0; mc < 4; ++mc) {
            if (job == 0) {
#pragma unroll
                for (int r = 0; r < 4; ++r) {
                    const int grow = rowbase + mc * 16 + quad * 4 + r;
                    // scale = (1/sqrt(32)) * log2(e): attn uses exp2
                    const float x = (acc[mc][nt][r] + bs) * 0.25503508f;
                    const int bb = grow >> 10, mm = grow & 1023;
                    qo[(((bb * 8 + nh) * 1024 + mm) << 5) + kk] = (_Float16)x;
                }
            } else if (job == 1) {
#pragma unroll
                for (int r = 0; r < 4; ++r) {
                    const int grow = rowbase + mc * 16 + quad * 4 + r;
                    const float x = acc[mc][nt][r] + bs;
                    const int bb = grow >> 12, ii = grow & 4095;
                    ko[(((bb * 8 + nh) * 4096 + ii) << 5) + kk] = (_Float16)x;
                }
            } else {
                // fragment-ordered V store: key = i0 + r, v = kk
                const int grow0 = rowbase + mc * 16 + quad * 4;
                const int bb = grow0 >> 12, i0 = grow0 & 4095;
                f16x4 pv;
#pragma unroll
                for (int r = 0; r < 4; ++r) {
                    float x = acc[mc][nt][r] + bs;
                    const float sg = 1.0f / (1.0f + __expf(-x));
                    pv[r] = (_Float16)(x * sg);
                }
                // lam = (kk&15) + ((i0>>2)&3)*16; (i0>>2)&3 == quad here
                *(f16x4*)(vo + (size_t)(bb * 8 + nh) * 131072 + (i0 >> 4) * 512
                             + ((kk & 15) + quad * 16) * 8 + (kk >> 4) * 4) = pv;
            }
        }
    }
}

// ---------------- attn: full-occupancy row-split, RACE-HARDENED -------------
// R12 structure (grid 1024 = 32 bn x 32 mt, 8 waves = 2 rg x 4 q-streams,
// 32-key tiles, LDS 32 KB -> 4 blocks/CU = 32 waves/CU) with the R12 race
// closed.  R12's failure (absmax 7.8e-2) was NOT a layout bug: the 2-buffer
// schedule reuses a buffer ONE barrier after its last read, and the raw
// `vmcnt(0)+s_barrier` asm neither drained lgkmcnt nor pinned the MFMAs
// (rule: hipcc may sink register-only MFMAs past inline-asm barriers), so a
// wave could cross the barrier with ds_reads in flight while another wave's
// DMA (or the epilogue zeroing, which overlaps stream 0) overwrote the LDS.
// Fixes: (1) sched_barrier(0) + `s_waitcnt vmcnt(0) lgkmcnt(0)` + s_barrier
// per step; (2) full __syncthreads() before the epilogue zeroing.
// Verified fragment layouts unchanged: K via pre-swizzled global source ->
// linear LDS; V from fragment-ordered vf; both reads ds_read_b128 at
// lane*16 -> zero bank conflicts.
__global__ __launch_bounds__(512, 8) void attn_kernel(
    const _Float16* __restrict__ qb,   // [32][1024][32] (pre-scaled log2e/sqrt32)
    const _Float16* __restrict__ kb,   // [32][4096][32]
    const _Float16* __restrict__ vf,   // [32][256][512] fragment-ordered halves
    float* __restrict__ out) {         // [4][1024][256]
    __shared__ __align__(16) char pool[32768];   // 4 streams x 2 bufs x 4 KB

    const int tid = threadIdx.x;
    const int lane = tid & 63, wid = tid >> 6;
    const int quad = lane >> 4, l16 = lane & 15;
    const int bn = blockIdx.x & 31, mt = blockIdx.x >> 5;   // mt 0..31
    const int b = bn >> 3, n = bn & 7;
    const int m0 = mt * 32;
    const int rg = wid & 1, q = wid >> 1;    // row group, key stream

    // ---- per-wave DMA assignments: 2 wave-loads (1 KB each) per step ----
    // j = 0..15: stream qj = j>>2, sub = j&3; sub<2 -> K subtile sub,
    // sub>=2 -> V subtile sub-2.  Both sources advance 1024 elems/step
    // (32 keys).  Stream layout: qj*8192 + buf*4096 + [K 2KB | V 2KB].
    const _Float16* gsrc[2];
    int ldsoff[2];
#pragma unroll
    for (int jj = 0; jj < 2; ++jj) {
        const int j = wid + jj * 8;              // 0..15
        const int qj = j >> 2, sub = j & 3;
        if (sub < 2) {   // K subtile: pre-swizzled source, linear LDS
            gsrc[jj] = kb + ((size_t)bn << 17)
                     + (size_t)(qj * 1024 + sub * 16 + (lane & 15)) * 32 + (lane >> 4) * 8;
            ldsoff[jj] = qj * 8192 + sub * 1024;
        } else {         // V subtile: vf is already fragment-ordered -> linear
            gsrc[jj] = vf + ((size_t)bn << 17)
                     + (size_t)(qj * 64 + (sub - 2)) * 512 + lane * 8;
            ldsoff[jj] = qj * 8192 + 2048 + (sub - 2) * 1024;
        }
    }

    // Q fragment (16 rows, L2-hot)
    const f16x8 qf = *(const f16x8*)(qb + (((size_t)(bn << 10) + m0 + rg * 16 + l16) << 5) + quad * 8);

    // per-lane read base: both K and V reads are b128 at lane*16
    const int rbase = q * 8192 + lane * 16;

    // prologue: DMA step 0 into buf 0
#pragma unroll
    for (int jj = 0; jj < 2; ++jj) {
        gl_lds16(gsrc[jj], pool + ldsoff[jj]);
        gsrc[jj] += 1024;
    }
    asm volatile("s_waitcnt vmcnt(0) lgkmcnt(0)\n\ts_barrier" ::: "memory");

    f32x4 acc0 = (f32x4){0.f, 0.f, 0.f, 0.f};   // out^T[v=quad*4+r   ][m=rg*16+l16]
    f32x4 acc1 = acc0;                           // out^T[v=16+quad*4+r][m=rg*16+l16]
    float ps0 = 0.f;

    for (int s = 0; s < 32; ++s) {
        if (s < 31) {   // issue step s+1 into the other buffer (EARLY --
                        // drains a full compute window later at the barrier)
            const int nb = ((s + 1) & 1) * 4096;
#pragma unroll
            for (int jj = 0; jj < 2; ++jj) {
                gl_lds16(gsrc[jj], pool + ldsoff[jj] + nb);
                gsrc[jj] += 1024;
            }
        }
        const char* base = pool + rbase + (s & 1) * 4096;
#pragma unroll
        for (int tloc = 0; tloc < 2; ++tloc) {
            const f16x8 kf = *(const f16x8*)(base + tloc * 1024);
            const f16x8 vv = *(const f16x8*)(base + 2048 + tloc * 1024);
            const f16x4 va0 = {vv[0], vv[1], vv[2], vv[3]};
            const f16x4 va1 = {vv[4], vv[5], vv[6], vv[7]};

            f32x4 s0 = __builtin_amdgcn_mfma_f32_16x16x32_f16(kf, qf, (f32x4){0.f,0.f,0.f,0.f}, 0, 0, 0);
            const float p0 = EXP2(s0[0]), p1 = EXP2(s0[1]), p2 = EXP2(s0[2]), p3 = EXP2(s0[3]);
            ps0 += (p0 + p1) + (p2 + p3);
            auto e0 = __builtin_amdgcn_cvt_pkrtz(p0, p1);
            auto e1 = __builtin_amdgcn_cvt_pkrtz(p2, p3);
            const f16x4 pb = {F16(e0[0]), F16(e0[1]), F16(e1[0]), F16(e1[1])};
            acc0 = __builtin_amdgcn_mfma_f32_16x16x16f16(va0, pb, acc0, 0, 0, 0);
            acc1 = __builtin_amdgcn_mfma_f32_16x16x16f16(va1, pb, acc1, 0, 0, 0);
        }
        if (s < 31) {
            // pin all reads/MFMAs of this step above the barrier, then drain
            // LDS reads (closes the 1-barrier buffer-reuse race) and the DMA.
            __builtin_amdgcn_sched_barrier(0);
            asm volatile("s_waitcnt vmcnt(0) lgkmcnt(0)\n\ts_barrier" ::: "memory");
        }
    }

    // ---- epilogue: 8-way (rg,q)-split combine in (now free) LDS ----
    __builtin_amdgcn_sched_barrier(0);
    __syncthreads();   // full drain: no wave still reading K/V buffers
    float* num = (float*)pool;                 // [32][33]
    float* den = (float*)(pool + 32 * 33 * 4); // [32]
    for (int i = tid; i < 32 * 33 + 32; i += 512) ((float*)pool)[i] = 0.f;
    __syncthreads();

    // sum exp-partials over the 4 quads (score rows live in quads)
    ps0 += __shfl_xor(ps0, 16); ps0 += __shfl_xor(ps0, 32);

    const int m = rg * 16 + l16;
#pragma unroll
    for (int r = 0; r < 4; ++r) {
        atomicAdd(&num[m * 33 + quad * 4 + r], acc0[r]);
        atomicAdd(&num[m * 33 + 16 + quad * 4 + r], acc1[r]);
    }
    if (quad == 0) atomicAdd(&den[m], ps0);
    __syncthreads();

    // store: 32 m x 32 v = 1024 f32 = 512 threads x one float2
    {
        const int mloc = tid >> 4, v2 = (tid & 15) * 2;
        const float inv = 1.0f / den[mloc];
        const float* nr = num + mloc * 33 + v2;
        float2 o = {nr[0] * inv, nr[1] * inv};
        *(float2*)(out + (((size_t)(b << 10) + m0 + mloc) << 8) + n * 32 + v2) = o;
    }
}

// ---------------- launch -----------------------------------------------------
extern "C" void kernel_launch(void* const* d_in, const int* in_sizes, int n_in,
                              void* d_out, int out_size, void* d_ws, size_t ws_size,
                              hipStream_t stream) {
    const float* blob = (const float*)d_in[0];
    const float* wq = (const float*)d_in[1];
    const float* bq = (const float*)d_in[2];
    const float* wk = (const float*)d_in[3];
    const float* bk = (const float*)d_in[4];
    const float* wv = (const float*)d_in[5];
    const float* bv = (const float*)d_in[6];
    float* out = (float*)d_out;

    char* ws = (char*)d_ws;
    _Float16* wt = (_Float16*)(ws);                    //   393,216 B
    _Float16* ko = (_Float16*)(ws + 393216);           // 8,388,608 B
    _Float16* vo = (_Float16*)(ws + 8781824);          // 8,388,608 B
    _Float16* qo = (_Float16*)(ws + 17170432);         // 2,097,152 B

    prep_kernel<<<192, 256, 0, stream>>>(wq, wk, wv, wt);
    proj_kernel<<<576, 256, 0, stream>>>(blob, wt, bq, bk, bv, qo, ko, vo);
    attn_kernel<<<1024, 512, 0, stream>>>(qo, ko, vo, out);
}

// Round 14
// 132.022 us; speedup vs baseline: 1.1072x; 1.1072x over previous
//
#include <hip/hip_runtime.h>

// B=4, H=W=64, D=256, N=8, K=V=32, H2=W2=32, HW=4096, M=1024 pooled/batch.
// FINAL (R14 = R11 verified optimum, 133.7 us measured):
//   prep (LDS transpose) -> proj (fused QKV GEMMs, W triple-buffer) ->
//   attn (R5 dataflow, 128-key tiles, 2-buf early-issue DMA pipeline).
// Lever ledger (all HW-tested): conflict-free fragment layouts WIN (R4/R5);
// counted-vmcnt DMA pipeline WIN (R3); W 2-step prefetch WIN (R9); LDS dedup
// REGRESS (R7); fewer barriers NEUTRAL (R11); direct-from-L2 REGRESS (R10,
// HBM spill); cross-block key-split DISASTER (R6, L2 coherence); full
// occupancy REGRESS (R13, sync cost > TLP gain).

typedef _Float16 f16x8 __attribute__((ext_vector_type(8)));
typedef _Float16 f16x4 __attribute__((ext_vector_type(4)));
typedef float    f32x4 __attribute__((ext_vector_type(4)));

#define F16(x) static_cast<_Float16>(x)

#if __has_builtin(__builtin_amdgcn_exp2f)
#define EXP2(x) __builtin_amdgcn_exp2f(x)
#else
#define EXP2(x) exp2f(x)
#endif

// async global->LDS DMA, 16 B per lane; lane i lands at (uniform base) + i*16
__device__ __forceinline__ void gl_lds16(const void* g, void* l) {
    __builtin_amdgcn_global_load_lds(
        (const __attribute__((address_space(1))) unsigned int*)g,
        (__attribute__((address_space(3))) unsigned int*)l, 16, 0, 0);
}

// ---------------- prep: weights -> f16 transposed Wt[mat][o][d] -------------
// LDS 32x33 tile transpose: coalesced f32 reads along o, contiguous f16
// writes along d.
__global__ __launch_bounds__(256) void prep_kernel(
    const float* __restrict__ wq, const float* __restrict__ wk,
    const float* __restrict__ wv, _Float16* __restrict__ wt) {
    __shared__ float t[32][33];
    const int blk = blockIdx.x;              // 192 = 3 mats x 64 tiles
    const int mat = blk >> 6;
    const int tile = blk & 63;
    const int d0 = (tile >> 3) * 32, o0 = (tile & 7) * 32;
    const float* w = (mat == 0) ? wq : (mat == 1 ? wk : wv);
    const int tx = threadIdx.x & 31, ty = threadIdx.x >> 5;   // ty 0..7
#pragma unroll
    for (int i = 0; i < 4; ++i)
        t[ty + i * 8][tx] = w[(d0 + ty + i * 8) * 256 + o0 + tx];
    __syncthreads();
#pragma unroll
    for (int i = 0; i < 4; ++i)
        wt[(mat << 16) + (o0 + ty + i * 8) * 256 + d0 + tx] = (_Float16)t[tx][ty + i * 8];
}

// ---------------- proj: all three 1x1-conv GEMMs in one launch --------------
// R9-verified: 64-row blocks, A LDS depth-2 pipeline, W register TRIPLE
// buffer (2-step prefetch distance -- covered the W L2 latency, -8 us).
// V output written FRAGMENT-ORDERED for attn (vf layout, validated round 4):
//   vf[bn][key>>4][lam*8 + (v>>4)*4 + (key&3)], lam = (v&15) + ((key>>2)&3)*16.
__global__ __launch_bounds__(256) void proj_kernel(
    const float* __restrict__ blob, const _Float16* __restrict__ wt,
    const float* __restrict__ bq, const float* __restrict__ bk, const float* __restrict__ bv,
    _Float16* __restrict__ qo, _Float16* __restrict__ ko, _Float16* __restrict__ vo) {
    __shared__ __align__(16) char atile[2][4096];   // [buf][64 rows x 32 k f16]

    const int tid = threadIdx.x;
    const int lane = tid & 63, wid = tid >> 6;
    const int quad = lane >> 4, l16 = lane & 15;
    int jb = blockIdx.x;                     // 576 = 64 q + 256 k + 256 v
    int job, rowblk;
    if (jb < 64)       { job = 0; rowblk = jb; }
    else if (jb < 320) { job = 1; rowblk = jb - 64; }
    else               { job = 2; rowblk = jb - 320; }
    const int rowbase = rowblk * 64;
    const int colbase = wid * 64;
    const _Float16* wmat = wt + ((size_t)job << 16);
    const float* bias = (job == 0) ? bq : (job == 1 ? bk : bv);

    // ---- staging assignment: 256 threads x 16 B granule of the A tile ----
    const int srow = tid >> 2, sc8 = tid & 3;            // row 0..63, 8-elem col
    const int sslot = srow * 4 + ((sc8 + (srow >> 2)) & 3);
    const float* aptr;                                    // global src base
    if (job == 0) {
        const int grow = rowbase + srow;
        const int bb = grow >> 10, y = (grow >> 5) & 31, x = grow & 31;
        aptr = blob + (((bb * 64 + 2 * y) * 64) + 2 * x) * 256 + sc8 * 8;
    } else {
        aptr = blob + (size_t)(rowbase + srow) * 256 + sc8 * 8;
    }

    // per-wave weight pointers
    const _Float16* wptr[4];
#pragma unroll
    for (int nt = 0; nt < 4; ++nt)
        wptr[nt] = wmat + (size_t)(colbase + nt * 16 + l16) * 256 + quad * 8;

    // af read base (per-lane, swizzled; mc adds 1024 B)
    const int aread = l16 * 64 + ((quad + (l16 >> 2)) & 3) * 16;

    f32x4 acc[4][4];
#pragma unroll
    for (int mc = 0; mc < 4; ++mc)
#pragma unroll
        for (int nt = 0; nt < 4; ++nt) acc[mc][nt] = (f32x4){0.f, 0.f, 0.f, 0.f};

    f16x8 wf[3][4];      // weight TRIPLE buffer (2-step prefetch distance)
    float4 ar[2][2];     // A-load double-buffer (8 f32 = one 16 B granule)

    auto A_LOAD = [&](int t, float4* dst) {
        const float* p = aptr + t * 32;
        if (job == 0) {
            float4 a0 = *(const float4*)(p);
            float4 a1 = *(const float4*)(p + 4);
            float4 b0 = *(const float4*)(p + 256);
            float4 b1 = *(const float4*)(p + 260);
            float4 c0 = *(const float4*)(p + 16384);
            float4 c1 = *(const float4*)(p + 16388);
            float4 d0 = *(const float4*)(p + 16640);
            float4 d1 = *(const float4*)(p + 16644);
            dst[0].x = fmaxf(fmaxf(a0.x, b0.x), fmaxf(c0.x, d0.x));
            dst[0].y = fmaxf(fmaxf(a0.y, b0.y), fmaxf(c0.y, d0.y));
            dst[0].z = fmaxf(fmaxf(a0.z, b0.z), fmaxf(c0.z, d0.z));
            dst[0].w = fmaxf(fmaxf(a0.w, b0.w), fmaxf(c0.w, d0.w));
            dst[1].x = fmaxf(fmaxf(a1.x, b1.x), fmaxf(c1.x, d1.x));
            dst[1].y = fmaxf(fmaxf(a1.y, b1.y), fmaxf(c1.y, d1.y));
            dst[1].z = fmaxf(fmaxf(a1.z, b1.z), fmaxf(c1.z, d1.z));
            dst[1].w = fmaxf(fmaxf(a1.w, b1.w), fmaxf(c1.w, d1.w));
        } else {
            dst[0] = *(const float4*)(p);
            dst[1] = *(const float4*)(p + 4);
        }
    };
    auto A_WRITE = [&](int buf, const float4* src) {
        auto c0 = __builtin_amdgcn_cvt_pkrtz(src[0].x, src[0].y);
        auto c1 = __builtin_amdgcn_cvt_pkrtz(src[0].z, src[0].w);
        auto c2 = __builtin_amdgcn_cvt_pkrtz(src[1].x, src[1].y);
        auto c3 = __builtin_amdgcn_cvt_pkrtz(src[1].z, src[1].w);
        f16x8 v = {F16(c0[0]), F16(c0[1]), F16(c1[0]), F16(c1[1]),
                   F16(c2[0]), F16(c2[1]), F16(c3[0]), F16(c3[1])};
        *(f16x8*)(atile[buf] + sslot * 16) = v;
    };
    auto W_LOAD = [&](int t, f16x8* dst) {
#pragma unroll
        for (int nt = 0; nt < 4; ++nt) dst[nt] = *(const f16x8*)(wptr[nt] + t * 32);
    };

    // ---- prologue: W 2 steps deep, A depth-2 ----
    W_LOAD(0, wf[0]);
    W_LOAD(1, wf[1]);
    A_LOAD(0, ar[0]);
    A_WRITE(0, ar[0]);
    A_LOAD(1, ar[1]);
    asm volatile("s_waitcnt lgkmcnt(0)\n\ts_barrier" ::: "memory");

#pragma unroll
    for (int s = 0; s < 8; ++s) {
        if (s < 6) W_LOAD(s + 2, wf[(s + 2) % 3]);   // 2-step W lookahead
        f16x8 af[4];
#pragma unroll
        for (int mc = 0; mc < 4; ++mc)
            af[mc] = *(const f16x8*)(atile[s & 1] + mc * 1024 + aread);
#pragma unroll
        for (int mc = 0; mc < 4; ++mc)
#pragma unroll
            for (int nt = 0; nt < 4; ++nt)
                acc[mc][nt] = __builtin_amdgcn_mfma_f32_16x16x32_f16(
                    af[mc], wf[s % 3][nt], acc[mc][nt], 0, 0, 0);
        if (s < 7) A_WRITE((s + 1) & 1, ar[(s + 1) & 1]);
        if (s < 6) A_LOAD(s + 2, ar[s & 1]);
        if (s < 7) asm volatile("s_waitcnt lgkmcnt(0)\n\ts_barrier" ::: "memory");
    }

    // ---- epilogue: bias / scale / swish + stores ----
#pragma unroll
    for (int nt = 0; nt < 4; ++nt) {
        const int o = colbase + nt * 16 + l16;
        const float bs = bias[o];
        const int nh = o >> 5, kk = o & 31;
#pragma unroll
        for (int mc = 0; mc < 4; ++mc) {
            if (job == 0) {
#pragma unroll
                for (int r = 0; r < 4; ++r) {
                    const int grow = rowbase + mc * 16 + quad * 4 + r;
                    // scale = (1/sqrt(32)) * log2(e): attn uses exp2
                    const float x = (acc[mc][nt][r] + bs) * 0.25503508f;
                    const int bb = grow >> 10, mm = grow & 1023;
                    qo[(((bb * 8 + nh) * 1024 + mm) << 5) + kk] = (_Float16)x;
                }
            } else if (job == 1) {
#pragma unroll
                for (int r = 0; r < 4; ++r) {
                    const int grow = rowbase + mc * 16 + quad * 4 + r;
                    const float x = acc[mc][nt][r] + bs;
                    const int bb = grow >> 12, ii = grow & 4095;
                    ko[(((bb * 8 + nh) * 4096 + ii) << 5) + kk] = (_Float16)x;
                }
            } else {
                // fragment-ordered V store: key = i0 + r, v = kk
                const int grow0 = rowbase + mc * 16 + quad * 4;
                const int bb = grow0 >> 12, i0 = grow0 & 4095;
                f16x4 pv;
#pragma unroll
                for (int r = 0; r < 4; ++r) {
                    float x = acc[mc][nt][r] + bs;
                    const float sg = 1.0f / (1.0f + __expf(-x));
                    pv[r] = (_Float16)(x * sg);
                }
                // lam = (kk&15) + ((i0>>2)&3)*16; (i0>>2)&3 == quad here
                *(f16x4*)(vo + (size_t)(bb * 8 + nh) * 131072 + (i0 >> 4) * 512
                             + ((kk & 15) + quad * 16) * 8 + (kk >> 4) * 4) = pv;
            }
        }
    }
}

// ---------------- attn: R5 dataflow, 128-key tiles, half the barriers -------
// grid 512 = 32 bn (XCD swizzle: bn%8==XCD) x 16 mt; block = 8 waves, 64 rows.
// wave (rg=wid&3, kc=wid>>2): q-rows [m0+rg*16,+16), keys [kc*2048,+2048).
// Verified dataflow (fragment-ordered LDS, conflict-free b128 reads at
// lane*16, cooperative gl_lds16 staging that keeps K/V in L2).  K-tile 128
// keys, 2 buffers (LDS 64 KB, 2 blocks/CU at grid 512), 16 steps.
// Per step each wave: issue 4 gl_lds16 for step s+1 (other buffer), compute
// 8 tloc subtiles on buffer s&1, then vmcnt(0)+s_barrier.  The drain sits a
// full 8-tloc compute window after issue -> effectively free.
__global__ __launch_bounds__(512, 4) void attn_kernel(
    const _Float16* __restrict__ qb,   // [32][1024][32] (pre-scaled log2e/sqrt32)
    const _Float16* __restrict__ kb,   // [32][4096][32]
    const _Float16* __restrict__ vf,   // [32][256][512] fragment-ordered halves
    float* __restrict__ out) {         // [4][1024][256]
    __shared__ __align__(16) char pool[65536];   // 2 streams x 2 bufs x 16 KB

    const int tid = threadIdx.x;
    const int lane = tid & 63, wid = tid >> 6;
    const int quad = lane >> 4, l16 = lane & 15;
    const int bn = blockIdx.x & 31, mt = blockIdx.x >> 5;
    const int b = bn >> 3, n = bn & 7;
    const int m0 = mt * 64;
    const int rg = wid & 3, kc = wid >> 2;

    // ---- per-wave DMA assignments: 4 wave-loads (1 KB each) per step ----
    // j = 0..31: stream kcj = j>>4, sub = j&15; sub<8 -> K subtile sub,
    // sub>=8 -> V subtile sub-8.  Both sources advance 4096 elems/step
    // (128 keys).  Stream layout: kcj*32768 + buf*16384 + [K 8KB | V 8KB].
    const _Float16* gsrc[4];
    int ldsoff[4];
#pragma unroll
    for (int jj = 0; jj < 4; ++jj) {
        const int j = wid + jj * 8;              // 0..31
        const int kcj = j >> 4, sub = j & 15;
        if (sub < 8) {   // K subtile: pre-swizzled source, linear LDS
            gsrc[jj] = kb + ((size_t)bn << 17)
                     + (size_t)(kcj * 2048 + sub * 16 + (lane & 15)) * 32 + (lane >> 4) * 8;
            ldsoff[jj] = kcj * 32768 + sub * 1024;
        } else {         // V subtile: vf is already fragment-ordered -> linear
            gsrc[jj] = vf + ((size_t)bn << 17)
                     + (size_t)(kcj * 128 + (sub - 8)) * 512 + lane * 8;
            ldsoff[jj] = kcj * 32768 + 8192 + (sub - 8) * 1024;
        }
    }

    // Q fragment (16 rows, L2-hot)
    const f16x8 qf = *(const f16x8*)(qb + (((size_t)(bn << 10) + m0 + rg * 16 + l16) << 5) + quad * 8);

    // per-lane read base: both K and V reads are b128 at lane*16
    const int rbase = kc * 32768 + lane * 16;

    // prologue: DMA step 0 into buf 0
#pragma unroll
    for (int jj = 0; jj < 4; ++jj) {
        gl_lds16(gsrc[jj], pool + ldsoff[jj]);
        gsrc[jj] += 4096;
    }
    asm volatile("s_waitcnt vmcnt(0)\n\ts_barrier" ::: "memory");   // step 0 ready

    f32x4 acc0 = (f32x4){0.f, 0.f, 0.f, 0.f};   // out^T[v=quad*4+r   ][m=rg*16+l16]
    f32x4 acc1 = acc0;                           // out^T[v=16+quad*4+r][m=rg*16+l16]
    float ps0 = 0.f;

    for (int s = 0; s < 16; ++s) {
        if (s < 15) {   // DMA step s+1 into the other buffer (issued EARLY --
                        // drains ~1000+ cyc later at this step's end barrier)
            const int nb = ((s + 1) & 1) * 16384;
#pragma unroll
            for (int jj = 0; jj < 4; ++jj) {
                gl_lds16(gsrc[jj], pool + ldsoff[jj] + nb);
                gsrc[jj] += 4096;
            }
        }
        const char* base = pool + rbase + (s & 1) * 16384;
#pragma unroll
        for (int tloc = 0; tloc < 8; ++tloc) {
            const f16x8 kf = *(const f16x8*)(base + tloc * 1024);
            const f16x8 vv = *(const f16x8*)(base + 8192 + tloc * 1024);
            const f16x4 va0 = {vv[0], vv[1], vv[2], vv[3]};
            const f16x4 va1 = {vv[4], vv[5], vv[6], vv[7]};

            f32x4 s0 = __builtin_amdgcn_mfma_f32_16x16x32_f16(kf, qf, (f32x4){0.f,0.f,0.f,0.f}, 0, 0, 0);
            const float p0 = EXP2(s0[0]), p1 = EXP2(s0[1]), p2 = EXP2(s0[2]), p3 = EXP2(s0[3]);
            ps0 += (p0 + p1) + (p2 + p3);
            auto e0 = __builtin_amdgcn_cvt_pkrtz(p0, p1);
            auto e1 = __builtin_amdgcn_cvt_pkrtz(p2, p3);
            const f16x4 pb = {F16(e0[0]), F16(e0[1]), F16(e1[0]), F16(e1[1])};
            acc0 = __builtin_amdgcn_mfma_f32_16x16x16f16(va0, pb, acc0, 0, 0, 0);
            acc1 = __builtin_amdgcn_mfma_f32_16x16x16f16(va1, pb, acc1, 0, 0, 0);
        }
        // step s+1's loads were issued before this step's compute -> the
        // vmcnt(0) drain is cheap; barrier also protects buf reuse.
        if (s < 15) asm volatile("s_waitcnt vmcnt(0)\n\ts_barrier" ::: "memory");
        else        asm volatile("s_barrier" ::: "memory");
    }

    // ---- epilogue: 2-way key-split combine in (now free) LDS ----
    float* num = (float*)pool;                 // [64][33]
    float* den = (float*)(pool + 64 * 33 * 4); // [64]
    for (int i = tid; i < 64 * 33 + 64; i += 512) ((float*)pool)[i] = 0.f;
    __syncthreads();

    // sum exp-partials over the 4 quads (score rows live in quads)
    ps0 += __shfl_xor(ps0, 16); ps0 += __shfl_xor(ps0, 32);

    const int m = rg * 16 + l16;
#pragma unroll
    for (int r = 0; r < 4; ++r) {
        atomicAdd(&num[m * 33 + quad * 4 + r], acc0[r]);
        atomicAdd(&num[m * 33 + 16 + quad * 4 + r], acc1[r]);
    }
    if (quad == 0) atomicAdd(&den[m], ps0);
    __syncthreads();

    // store: 64 m x 32 v = 2048 f32 = 512 threads x one float4
    {
        const int mloc = tid >> 3, v4 = (tid & 7) * 4;
        const float inv = 1.0f / den[mloc];
        const float* nr = num + mloc * 33 + v4;
        float4 o = {nr[0] * inv, nr[1] * inv, nr[2] * inv, nr[3] * inv};
        *(float4*)(out + (((size_t)(b << 10) + m0 + mloc) << 8) + n * 32 + v4) = o;
    }
}

// ---------------- launch -----------------------------------------------------
extern "C" void kernel_launch(void* const* d_in, const int* in_sizes, int n_in,
                              void* d_out, int out_size, void* d_ws, size_t ws_size,
                              hipStream_t stream) {
    const float* blob = (const float*)d_in[0];
    const float* wq = (const float*)d_in[1];
    const float* bq = (const float*)d_in[2];
    const float* wk = (const float*)d_in[3];
    const float* bk = (const float*)d_in[4];
    const float* wv = (const float*)d_in[5];
    const float* bv = (const float*)d_in[6];
    float* out = (float*)d_out;

    char* ws = (char*)d_ws;
    _Float16* wt = (_Float16*)(ws);                    //   393,216 B
    _Float16* ko = (_Float16*)(ws + 393216);           // 8,388,608 B
    _Float16* vo = (_Float16*)(ws + 8781824);          // 8,388,608 B
    _Float16* qo = (_Float16*)(ws + 17170432);         // 2,097,152 B

    prep_kernel<<<192, 256, 0, stream>>>(wq, wk, wv, wt);
    proj_kernel<<<576, 256, 0, stream>>>(blob, wt, bq, bk, bv, qo, ko, vo);
    attn_kernel<<<512, 512, 0, stream>>>(qo, ko, vo, out);
}